// Round 2
// baseline (102.380 us; speedup 1.0000x reference)
//
#include <hip/hip_runtime.h>
#include <hip/hip_bf16.h>

#define NB 8
#define SEQ 2048
#define DIN 1024
#define DH 64

typedef __attribute__((ext_vector_type(8))) short bf16x8;
typedef __attribute__((ext_vector_type(4))) float f32x4;

static __device__ __forceinline__ unsigned short f2bf(float f) {
    unsigned int u = __builtin_bit_cast(unsigned int, f);
    unsigned int r = (u + 0x7FFFu + ((u >> 16) & 1u)) >> 16;
    return (unsigned short)r;
}

// ---------------- prep: Wt[mat][col][k] = bf16(W[k][col]);  bias = mask ? -1e30 : 0
__global__ __launch_bounds__(256) void prep_kernel(
    const float* __restrict__ Wq, const float* __restrict__ Wk, const float* __restrict__ Wv,
    const int* __restrict__ mask, unsigned short* __restrict__ Wt, float* __restrict__ bias)
{
    int i = blockIdx.x * 256 + threadIdx.x;
    if (i < 3 * DH * DIN) {
        int mat = i >> 16;            // DH*DIN = 65536
        int c   = (i >> 10) & 63;
        int k   = i & 1023;
        const float* W = (mat == 0) ? Wq : ((mat == 1) ? Wk : Wv);
        Wt[i] = f2bf(W[k * DH + c]);
    } else {
        int j = i - 3 * DH * DIN;
        if (j < NB * SEQ) bias[j] = mask[j] ? -1e30f : 0.0f;
    }
}

// ---------------- QKV GEMM: X[16384x1024] fp32 -> Qb,Kb [16384x64] bf16, Vt [8][64][2048] bf16
#define QBM 32
#define QBK 128

__global__ __launch_bounds__(256, 4) void qkv_kernel(
    const float* __restrict__ X, const unsigned short* __restrict__ Wt,
    const float* __restrict__ bq, const float* __restrict__ bk, const float* __restrict__ bv,
    unsigned short* __restrict__ Qb, unsigned short* __restrict__ Kb, unsigned short* __restrict__ Vt)
{
    __shared__ __align__(16) short As[QBM][QBK];   // XOR-swizzled, 8 KiB

    const int tid = threadIdx.x;
    const int w   = tid >> 6;       // wave 0..3 -> 48-col stripe
    const int l   = tid & 63;
    const int l15 = l & 15;
    const int lq  = l >> 4;
    const int row0 = blockIdx.x * QBM;

    f32x4 acc[2][3] = {};

    const int srow = tid >> 3;            // 0..31
    const int scg  = (tid & 7) * 16;      // col base within 128
    const float* xb = X + (size_t)(row0 + srow) * DIN + scg;
    const int swcol0 = (scg)     ^ ((srow & 7) << 3);
    const int swcol1 = (scg + 8) ^ ((srow & 7) << 3);

    // weight base pointers for this wave's 3 column-frags
    const unsigned short* wp[3];
    #pragma unroll
    for (int n = 0; n < 3; ++n) {
        int col = w * 48 + n * 16 + l15;
        int mat = col >> 6, c = col & 63;
        wp[n] = Wt + ((size_t)(mat * DH + c)) * DIN + lq * 8;
    }

    float4 pf0 = *(const float4*)(xb + 0);
    float4 pf1 = *(const float4*)(xb + 4);
    float4 pf2 = *(const float4*)(xb + 8);
    float4 pf3 = *(const float4*)(xb + 12);

    for (int step = 0; step < DIN / QBK; ++step) {
        bf16x8 sv0, sv1;
        sv0[0] = (short)f2bf(pf0.x); sv0[1] = (short)f2bf(pf0.y);
        sv0[2] = (short)f2bf(pf0.z); sv0[3] = (short)f2bf(pf0.w);
        sv0[4] = (short)f2bf(pf1.x); sv0[5] = (short)f2bf(pf1.y);
        sv0[6] = (short)f2bf(pf1.z); sv0[7] = (short)f2bf(pf1.w);
        sv1[0] = (short)f2bf(pf2.x); sv1[1] = (short)f2bf(pf2.y);
        sv1[2] = (short)f2bf(pf2.z); sv1[3] = (short)f2bf(pf2.w);
        sv1[4] = (short)f2bf(pf3.x); sv1[5] = (short)f2bf(pf3.y);
        sv1[6] = (short)f2bf(pf3.z); sv1[7] = (short)f2bf(pf3.w);

        if (step < DIN / QBK - 1) {      // prefetch next X tile
            const float* xn = xb + (step + 1) * QBK;
            pf0 = *(const float4*)(xn + 0);
            pf1 = *(const float4*)(xn + 4);
            pf2 = *(const float4*)(xn + 8);
            pf3 = *(const float4*)(xn + 12);
        }

        __syncthreads();
        *(bf16x8*)&As[srow][swcol0] = sv0;
        *(bf16x8*)&As[srow][swcol1] = sv1;
        __syncthreads();

        #pragma unroll
        for (int kk = 0; kk < 4; ++kk) {
            bf16x8 bfr[3];
            #pragma unroll
            for (int n = 0; n < 3; ++n)
                bfr[n] = *(const bf16x8*)(wp[n] + (size_t)step * QBK + kk * 32);
            bf16x8 a[2];
            #pragma unroll
            for (int m = 0; m < 2; ++m) {
                int row = m * 16 + l15;
                int col = (kk * 32 + lq * 8) ^ ((row & 7) << 3);
                a[m] = *(const bf16x8*)&As[row][col];
            }
            #pragma unroll
            for (int m = 0; m < 2; ++m)
                #pragma unroll
                for (int n = 0; n < 3; ++n)
                    acc[m][n] = __builtin_amdgcn_mfma_f32_16x16x32_bf16(a[m], bfr[n], acc[m][n], 0, 0, 0);
        }
    }

    // epilogue
    #pragma unroll
    for (int n = 0; n < 3; ++n) {
        int col = w * 48 + n * 16 + l15;
        int mat = col >> 6, c = col & 63;
        float badd = ((mat == 0) ? bq : ((mat == 1) ? bk : bv))[c];
        #pragma unroll
        for (int m = 0; m < 2; ++m) {
            #pragma unroll
            for (int reg = 0; reg < 4; ++reg) {
                int row = row0 + m * 16 + lq * 4 + reg;
                unsigned short v16 = f2bf(acc[m][n][reg] + badd);
                if (mat == 0)      Qb[(size_t)row * DH + c] = v16;
                else if (mat == 1) Kb[(size_t)row * DH + c] = v16;
                else {
                    int bb = row >> 11, ss = row & 2047;
                    Vt[((size_t)(bb * DH + c)) * SEQ + ss] = v16;
                }
            }
        }
    }
}

// ---------------- flash attention (fixed-max softmax, no per-iter reductions)
// block = (batch, 16 q-rows); 4 waves x 512 keys each, KVB=128 per iter
#define KVB 128

__global__ __launch_bounds__(256, 4) void attn_kernel(
    const unsigned short* __restrict__ Qb, const unsigned short* __restrict__ Kb,
    const unsigned short* __restrict__ Vt, const float* __restrict__ bias,
    float* __restrict__ out)
{
    __shared__ __align__(16) short ps[4][16][128];   // 16 KiB; aliased as float [4][16][64] for merge
    __shared__ float sml[4][16];

    const int tid = threadIdx.x;
    const int w   = tid >> 6;
    const int l   = tid & 63;
    const int l15 = l & 15;
    const int lq  = l >> 4;

    int bid = blockIdx.x;
    bid = (bid & 7) * 128 + (bid >> 3);   // XCD swizzle: one batch per XCD
    const int b  = bid >> 7;
    const int q0 = (bid & 127) * 16;

    // persistent Q fragments
    const unsigned short* qp = Qb + ((size_t)(b * SEQ + q0 + l15)) * DH + lq * 8;
    bf16x8 aq0 = *(const bf16x8*)qp;
    bf16x8 aq1 = *(const bf16x8*)(qp + 32);

    f32x4 lrow = {0.f, 0.f, 0.f, 0.f};
    f32x4 o[4];
    o[0] = f32x4{0,0,0,0}; o[1] = o[0]; o[2] = o[0]; o[3] = o[0];

    const float rscale = 0.022097086912079612f;  // 1/sqrt(2048)

    for (int kt = 0; kt < 4; ++kt) {
        const int key0 = w * 512 + kt * KVB;

        // ---- QK^T over 128 keys (8 n-frags, two halves to bound VGPR)
        f32x4 s[8];
        #pragma unroll
        for (int n = 0; n < 8; ++n) s[n] = f32x4{0,0,0,0};

        const unsigned short* kp = Kb + ((size_t)(b * SEQ + key0 + l15)) * DH + lq * 8;
        #pragma unroll
        for (int h = 0; h < 2; ++h) {
            bf16x8 bk8[4][2];
            #pragma unroll
            for (int n = 0; n < 4; ++n) {
                const unsigned short* kpp = kp + (size_t)(h * 64 + n * 16) * DH;
                bk8[n][0] = *(const bf16x8*)kpp;
                bk8[n][1] = *(const bf16x8*)(kpp + 32);
            }
            #pragma unroll
            for (int n = 0; n < 4; ++n) {
                s[h*4+n] = __builtin_amdgcn_mfma_f32_16x16x32_bf16(aq0, bk8[n][0], s[h*4+n], 0, 0, 0);
                s[h*4+n] = __builtin_amdgcn_mfma_f32_16x16x32_bf16(aq1, bk8[n][1], s[h*4+n], 0, 0, 0);
            }
        }

        // ---- p = exp(s*scale + bias); accumulate per-lane l; store bf16 P (swizzled)
        const float* bp = bias + b * SEQ + key0 + l15;
        #pragma unroll
        for (int n = 0; n < 8; ++n) {
            float bvv = bp[n * 16];
            #pragma unroll
            for (int r = 0; r < 4; ++r) {
                float p = __expf(fmaf(s[n][r], rscale, bvv));
                lrow[r] += p;
                int row = lq * 4 + r;
                int col = (n * 16 + l15) ^ ((row & 7) << 3);
                ps[w][row][col] = (short)f2bf(p);
            }
        }

        // ---- PV: P (16x128) x V (128x64)
        bf16x8 pa[4];
        #pragma unroll
        for (int kk = 0; kk < 4; ++kk) {
            int col = (kk * 32 + lq * 8) ^ ((l15 & 7) << 3);
            pa[kk] = *(const bf16x8*)&ps[w][l15][col];
        }
        const unsigned short* vp = Vt + ((size_t)(b * DH + l15)) * SEQ + key0 + lq * 8;
        #pragma unroll
        for (int kk = 0; kk < 4; ++kk) {
            bf16x8 bv8[4];
            #pragma unroll
            for (int n = 0; n < 4; ++n)
                bv8[n] = *(const bf16x8*)(vp + (size_t)(n * 16) * SEQ + kk * 32);
            #pragma unroll
            for (int n = 0; n < 4; ++n)
                o[n] = __builtin_amdgcn_mfma_f32_16x16x32_bf16(pa[kk], bv8[n], o[n], 0, 0, 0);
        }
    }

    // ---- l: reduce per-lane partials across the 16 key-columns (once)
    #pragma unroll
    for (int off = 1; off < 16; off <<= 1)
        #pragma unroll
        for (int r = 0; r < 4; ++r) lrow[r] += __shfl_xor(lrow[r], off);
    if (l15 == 0) {
        #pragma unroll
        for (int r = 0; r < 4; ++r) sml[w][lq * 4 + r] = lrow[r];
    }

    __syncthreads();   // all waves done with their ps region (also memory-fences the alias below)

    float (*so)[16][64] = reinterpret_cast<float (*)[16][64]>(&ps[0][0][0]);
    #pragma unroll
    for (int n = 0; n < 4; ++n)
        #pragma unroll
        for (int r = 0; r < 4; ++r)
            so[w][lq * 4 + r][n * 16 + l15] = o[n][r];
    __syncthreads();

    // final: each thread writes one float4 of the 16x64 output tile
    {
        int q  = tid >> 4;
        int d0 = (tid & 15) * 4;
        float lt = sml[0][q] + sml[1][q] + sml[2][q] + sml[3][q];
        float inv = 1.0f / lt;
        float vx[4];
        #pragma unroll
        for (int i = 0; i < 4; ++i)
            vx[i] = (so[0][q][d0 + i] + so[1][q][d0 + i] + so[2][q][d0 + i] + so[3][q][d0 + i]) * inv;
        float4 r4; r4.x = vx[0]; r4.y = vx[1]; r4.z = vx[2]; r4.w = vx[3];
        *(float4*)(out + ((size_t)(b * SEQ + q0 + q)) * DH + d0) = r4;
    }
}

extern "C" void kernel_launch(void* const* d_in, const int* in_sizes, int n_in,
                              void* d_out, int out_size, void* d_ws, size_t ws_size,
                              hipStream_t stream) {
    const float* X    = (const float*)d_in[0];
    const int*   mask = (const int*)d_in[1];
    const float* Wq   = (const float*)d_in[2];
    const float* bq   = (const float*)d_in[3];
    const float* Wk   = (const float*)d_in[4];
    const float* bk   = (const float*)d_in[5];
    const float* Wv   = (const float*)d_in[6];
    const float* bv   = (const float*)d_in[7];
    float* out = (float*)d_out;

    char* ws = (char*)d_ws;
    unsigned short* Qb = (unsigned short*)(ws);                       // 2 MiB
    unsigned short* Kb = (unsigned short*)(ws + (2u << 20));          // 2 MiB
    unsigned short* Vt = (unsigned short*)(ws + (4u << 20));          // 2 MiB
    unsigned short* Wt = (unsigned short*)(ws + (6u << 20));          // 384 KiB
    float* bias        = (float*)(ws + (6u << 20) + 3 * DH * DIN * 2); // 64 KiB

    prep_kernel<<<832, 256, 0, stream>>>(Wq, Wk, Wv, mask, Wt, bias);
    qkv_kernel<<<512, 256, 0, stream>>>(X, Wt, bq, bk, bv, Qb, Kb, Vt);
    attn_kernel<<<1024, 256, 0, stream>>>(Qb, Kb, Vt, bias, out);
}

// Round 3
// 55.743 us; speedup vs baseline: 1.8366x; 1.8366x over previous
//
#include <hip/hip_runtime.h>
#include <hip/hip_bf16.h>

#define NB 8
#define SEQ 2048
#define DIN 1024
#define DH 64

typedef __attribute__((ext_vector_type(8))) short bf16x8;
typedef __attribute__((ext_vector_type(4))) float f32x4;

static __device__ __forceinline__ unsigned short f2bf(float f) {
    unsigned int u = __builtin_bit_cast(unsigned int, f);
    unsigned int r = (u + 0x7FFFu + ((u >> 16) & 1u)) >> 16;
    return (unsigned short)r;
}

// ---------------- prep:
// Wfrag packed in MFMA-B-fragment-linear order:
//   idx = (cg*32 + kk)*512 + cl*32 + kq*8 + ke
//   where col = cg*16+cl (0..191, mat=col>>6), k = kk*32 + kq*8 + ke
// bias = mask ? -1e30 : 0
__global__ __launch_bounds__(256) void prep_kernel(
    const float* __restrict__ Wq, const float* __restrict__ Wk, const float* __restrict__ Wv,
    const int* __restrict__ mask, unsigned short* __restrict__ Wfrag, float* __restrict__ bias)
{
    int i = blockIdx.x * 256 + threadIdx.x;
    if (i < 3 * DH * DIN) {
        int cg = i >> 14;
        int kk = (i >> 9) & 31;
        int e  = i & 511;
        int cl = e >> 5;
        int kq = (e >> 3) & 3;
        int ke = e & 7;
        int col = cg * 16 + cl;
        int mat = col >> 6, c = col & 63;
        int k = kk * 32 + kq * 8 + ke;
        const float* W = (mat == 0) ? Wq : ((mat == 1) ? Wk : Wv);
        Wfrag[i] = f2bf(W[k * DH + c]);
    } else {
        int j = i - 3 * DH * DIN;
        if (j < NB * SEQ) bias[j] = mask[j] ? -1e30f : 0.0f;
    }
}

// ---------------- QKV GEMM: X[16384x1024] fp32 -> Qb,Kb [16384x64] bf16, Vt [8][64][2048] bf16
#define QBK 128

__global__ __launch_bounds__(256, 4) void qkv_kernel(
    const float* __restrict__ X, const unsigned short* __restrict__ Wfrag,
    const float* __restrict__ bq, const float* __restrict__ bk, const float* __restrict__ bv,
    unsigned short* __restrict__ Qb, unsigned short* __restrict__ Kb, unsigned short* __restrict__ Vt)
{
    __shared__ __align__(16) short As[32][QBK];   // XOR-swizzled

    const int tid = threadIdx.x;
    const int w   = tid >> 6;
    const int l   = tid & 63;
    const int l15 = l & 15;
    const int lq  = l >> 4;
    const int row0 = blockIdx.x * 32;

    f32x4 acc[2][3] = {};

    const int srow = tid >> 3;            // 0..31
    const int scg  = (tid & 7) * 16;      // col base within 128
    const float* xb = X + (size_t)(row0 + srow) * DIN + scg;
    const int swcol0 = (scg)     ^ ((srow & 7) << 3);
    const int swcol1 = (scg + 8) ^ ((srow & 7) << 3);

    // fragment-linear W pointers (coalesced 1KB loads)
    const unsigned short* wfb[3];
    #pragma unroll
    for (int n = 0; n < 3; ++n)
        wfb[n] = Wfrag + (size_t)((w * 3 + n) * 32) * 512 + (l15 * 4 + lq) * 8;

    float4 pf0 = *(const float4*)(xb + 0);
    float4 pf1 = *(const float4*)(xb + 4);
    float4 pf2 = *(const float4*)(xb + 8);
    float4 pf3 = *(const float4*)(xb + 12);

    for (int step = 0; step < DIN / QBK; ++step) {
        bf16x8 sv0, sv1;
        sv0[0] = (short)f2bf(pf0.x); sv0[1] = (short)f2bf(pf0.y);
        sv0[2] = (short)f2bf(pf0.z); sv0[3] = (short)f2bf(pf0.w);
        sv0[4] = (short)f2bf(pf1.x); sv0[5] = (short)f2bf(pf1.y);
        sv0[6] = (short)f2bf(pf1.z); sv0[7] = (short)f2bf(pf1.w);
        sv1[0] = (short)f2bf(pf2.x); sv1[1] = (short)f2bf(pf2.y);
        sv1[2] = (short)f2bf(pf2.z); sv1[3] = (short)f2bf(pf2.w);
        sv1[4] = (short)f2bf(pf3.x); sv1[5] = (short)f2bf(pf3.y);
        sv1[6] = (short)f2bf(pf3.z); sv1[7] = (short)f2bf(pf3.w);

        if (step < DIN / QBK - 1) {
            const float* xn = xb + (step + 1) * QBK;
            pf0 = *(const float4*)(xn + 0);
            pf1 = *(const float4*)(xn + 4);
            pf2 = *(const float4*)(xn + 8);
            pf3 = *(const float4*)(xn + 12);
        }

        __syncthreads();
        *(bf16x8*)&As[srow][swcol0] = sv0;
        *(bf16x8*)&As[srow][swcol1] = sv1;
        __syncthreads();

        #pragma unroll
        for (int kkl = 0; kkl < 4; ++kkl) {
            int kk = step * 4 + kkl;
            bf16x8 bfr[3];
            #pragma unroll
            for (int n = 0; n < 3; ++n)
                bfr[n] = *(const bf16x8*)(wfb[n] + kk * 512);
            bf16x8 a[2];
            #pragma unroll
            for (int m = 0; m < 2; ++m) {
                int row = m * 16 + l15;
                int col = (kkl * 32 + lq * 8) ^ ((row & 7) << 3);
                a[m] = *(const bf16x8*)&As[row][col];
            }
            #pragma unroll
            for (int m = 0; m < 2; ++m)
                #pragma unroll
                for (int n = 0; n < 3; ++n)
                    acc[m][n] = __builtin_amdgcn_mfma_f32_16x16x32_bf16(a[m], bfr[n], acc[m][n], 0, 0, 0);
        }
    }

    // epilogue
    #pragma unroll
    for (int n = 0; n < 3; ++n) {
        int col = w * 48 + n * 16 + l15;
        int mat = col >> 6, c = col & 63;
        float badd = ((mat == 0) ? bq : ((mat == 1) ? bk : bv))[c];
        #pragma unroll
        for (int m = 0; m < 2; ++m) {
            #pragma unroll
            for (int reg = 0; reg < 4; ++reg) {
                int row = row0 + m * 16 + lq * 4 + reg;
                unsigned short v16 = f2bf(acc[m][n][reg] + badd);
                if (mat == 0)      Qb[(size_t)row * DH + c] = v16;
                else if (mat == 1) Kb[(size_t)row * DH + c] = v16;
                else {
                    int bb = row >> 11, ss = row & 2047;
                    Vt[((size_t)(bb * DH + c)) * SEQ + ss] = v16;
                }
            }
        }
    }
}

// ---------------- flash attention, LDS-staged K/V tiles
// block = 32 q-rows, 4 waves; loop over 16 tiles of 128 keys; wave w owns keys [w*32,w*32+32) per tile
#define KT 128
#define NT (SEQ / KT)

__global__ __launch_bounds__(256, 2) void attn_kernel(
    const unsigned short* __restrict__ Qb, const unsigned short* __restrict__ Kb,
    const unsigned short* __restrict__ Vt, const float* __restrict__ bias,
    float* __restrict__ out)
{
    __shared__ __align__(16) short Ks[2][KT][DH];    // 32 KiB, swizzled: colB ^= (row&7)<<4
    __shared__ __align__(16) short Vs[2][DH][KT];    // 32 KiB, swizzled: colB ^= (d&7)<<4
    __shared__ __align__(16) short ps[128][40];      // 10 KiB per-wave P buffer (stride 40 shorts)
    __shared__ float sml[4][32];

    const int tid = threadIdx.x;
    const int w   = tid >> 6;
    const int l   = tid & 63;
    const int l15 = l & 15;
    const int lq  = l >> 4;

    int bid = blockIdx.x;
    bid = (bid & 7) * 64 + (bid >> 3);   // XCD swizzle: one batch per XCD (512 blocks, 64/batch)
    const int b  = bid >> 6;
    const int q0 = (bid & 63) * 32;

    // persistent Q fragments (2 m-frags x 2 kk)
    bf16x8 aq[2][2];
    #pragma unroll
    for (int m = 0; m < 2; ++m)
        #pragma unroll
        for (int kk = 0; kk < 2; ++kk)
            aq[m][kk] = *(const bf16x8*)(Qb + ((size_t)(b * SEQ + q0 + m * 16 + l15)) * DH + kk * 32 + lq * 8);

    // staging thread->element mapping
    const int krow = tid >> 3;             // 0..31 (per-issue row block of 32)
    const int kcolb = (tid & 7) * 16;      // byte col in 128B row
    const int kdst = (kcolb ^ ((krow & 7) << 4)) >> 1;   // swizzled short col
    const int vrow = tid >> 4;             // 0..15 (per-issue row block of 16)
    const int vcolb = (tid & 15) * 16;     // byte col in 256B row
    const int vdst = (vcolb ^ ((vrow & 7) << 4)) >> 1;

    const unsigned short* Kbase = Kb + (size_t)(b * SEQ) * DH + (kcolb >> 1);
    const unsigned short* Vbase = Vt + (size_t)(b * DH) * SEQ + (vcolb >> 1) - 0;

    bf16x8 kr[4], vr[4];
    #pragma unroll
    for (int i = 0; i < 4; ++i) {
        kr[i] = *(const bf16x8*)(Kbase + (size_t)(i * 32 + krow) * DH);
        vr[i] = *(const bf16x8*)(Vt + ((size_t)(b * DH + i * 16 + vrow)) * SEQ + (vcolb >> 1));
    }

    f32x4 o[2][4];
    #pragma unroll
    for (int m = 0; m < 2; ++m)
        #pragma unroll
        for (int n = 0; n < 4; ++n) o[m][n] = f32x4{0, 0, 0, 0};
    float lr[2][4] = {};

    const float rscale = 0.022097086912079612f;  // 1/sqrt(2048)
    const int kw = w * 32;                       // wave's key offset within tile

    for (int t = 0; t < NT; ++t) {
        const int cur = t & 1;

        // write staged regs -> LDS (swizzled dest)
        #pragma unroll
        for (int i = 0; i < 4; ++i) *(bf16x8*)&Ks[cur][i * 32 + krow][kdst] = kr[i];
        #pragma unroll
        for (int i = 0; i < 4; ++i) *(bf16x8*)&Vs[cur][i * 16 + vrow][vdst] = vr[i];

        // early-issue next tile's loads (hidden under compute)
        if (t + 1 < NT) {
            const int key0n = (t + 1) * KT;
            #pragma unroll
            for (int i = 0; i < 4; ++i) {
                kr[i] = *(const bf16x8*)(Kbase + (size_t)(key0n + i * 32 + krow) * DH);
                vr[i] = *(const bf16x8*)(Vt + ((size_t)(b * DH + i * 16 + vrow)) * SEQ + key0n + (vcolb >> 1));
            }
        }

        __syncthreads();

        // ---- QK^T: 32 q x 32 keys
        bf16x8 bkf[2][2];
        #pragma unroll
        for (int n = 0; n < 2; ++n)
            #pragma unroll
            for (int kk = 0; kk < 2; ++kk) {
                int col = (kk * 32 + lq * 8) ^ ((l15 & 7) << 3);
                bkf[n][kk] = *(const bf16x8*)&Ks[cur][kw + n * 16 + l15][col];
            }
        f32x4 s[2][2];
        #pragma unroll
        for (int m = 0; m < 2; ++m)
            #pragma unroll
            for (int n = 0; n < 2; ++n) s[m][n] = f32x4{0, 0, 0, 0};
        #pragma unroll
        for (int kk = 0; kk < 2; ++kk)
            #pragma unroll
            for (int m = 0; m < 2; ++m)
                #pragma unroll
                for (int n = 0; n < 2; ++n)
                    s[m][n] = __builtin_amdgcn_mfma_f32_16x16x32_bf16(aq[m][kk], bkf[n][kk], s[m][n], 0, 0, 0);

        // ---- p = exp(s*scale + bias); per-lane partial l; P -> ps
        float bb0 = bias[b * SEQ + t * KT + kw + l15];
        float bb1 = bias[b * SEQ + t * KT + kw + 16 + l15];
        #pragma unroll
        for (int m = 0; m < 2; ++m)
            #pragma unroll
            for (int n = 0; n < 2; ++n) {
                float bvv = n ? bb1 : bb0;
                #pragma unroll
                for (int r = 0; r < 4; ++r) {
                    float p = __expf(fmaf(s[m][n][r], rscale, bvv));
                    lr[m][r] += p;
                    ps[w * 32 + m * 16 + lq * 4 + r][n * 16 + l15] = (short)f2bf(p);
                }
            }

        // ---- PV: P(32x32) x V(32x64)
        bf16x8 pa[2];
        #pragma unroll
        for (int m = 0; m < 2; ++m)
            pa[m] = *(const bf16x8*)&ps[w * 32 + m * 16 + l15][lq * 8];
        bf16x8 bvf[4];
        #pragma unroll
        for (int n = 0; n < 4; ++n) {
            int col = (kw + lq * 8) ^ ((l15 & 7) << 3);
            bvf[n] = *(const bf16x8*)&Vs[cur][n * 16 + l15][col];
        }
        #pragma unroll
        for (int m = 0; m < 2; ++m)
            #pragma unroll
            for (int n = 0; n < 4; ++n)
                o[m][n] = __builtin_amdgcn_mfma_f32_16x16x32_bf16(pa[m], bvf[n], o[m][n], 0, 0, 0);
        // no trailing barrier needed: next iter writes the other buffer
    }

    // ---- l: reduce per-lane partials across the 16 key-columns
    #pragma unroll
    for (int off = 1; off < 16; off <<= 1)
        #pragma unroll
        for (int m = 0; m < 2; ++m)
            #pragma unroll
            for (int r = 0; r < 4; ++r) lr[m][r] += __shfl_xor(lr[m][r], off);
    if (l15 == 0) {
        #pragma unroll
        for (int m = 0; m < 2; ++m)
            #pragma unroll
            for (int r = 0; r < 4; ++r) sml[w][m * 16 + lq * 4 + r] = lr[m][r];
    }
    __syncthreads();   // all compute done; safe to reuse Ks as merge area

    float (*so)[32][64] = reinterpret_cast<float (*)[32][64]>(&Ks[0][0][0]);  // 32 KiB
    #pragma unroll
    for (int m = 0; m < 2; ++m)
        #pragma unroll
        for (int n = 0; n < 4; ++n)
            #pragma unroll
            for (int r = 0; r < 4; ++r)
                so[w][m * 16 + lq * 4 + r][n * 16 + l15] = o[m][n][r];
    __syncthreads();

    // final: 4-wave sum, divide by total l, store
    {
        int q  = tid >> 3;
        int d0 = (tid & 7) * 8;
        float lt = sml[0][q] + sml[1][q] + sml[2][q] + sml[3][q];
        float inv = 1.0f / lt;
        float vx[8];
        #pragma unroll
        for (int j = 0; j < 8; ++j)
            vx[j] = (so[0][q][d0 + j] + so[1][q][d0 + j] + so[2][q][d0 + j] + so[3][q][d0 + j]) * inv;
        float* op = out + ((size_t)(b * SEQ + q0 + q)) * DH + d0;
        float4 r0; r0.x = vx[0]; r0.y = vx[1]; r0.z = vx[2]; r0.w = vx[3];
        float4 r1; r1.x = vx[4]; r1.y = vx[5]; r1.z = vx[6]; r1.w = vx[7];
        *(float4*)op = r0;
        *(float4*)(op + 4) = r1;
    }
}

extern "C" void kernel_launch(void* const* d_in, const int* in_sizes, int n_in,
                              void* d_out, int out_size, void* d_ws, size_t ws_size,
                              hipStream_t stream) {
    const float* X    = (const float*)d_in[0];
    const int*   mask = (const int*)d_in[1];
    const float* Wq   = (const float*)d_in[2];
    const float* bq   = (const float*)d_in[3];
    const float* Wk   = (const float*)d_in[4];
    const float* bk   = (const float*)d_in[5];
    const float* Wv   = (const float*)d_in[6];
    const float* bv   = (const float*)d_in[7];
    float* out = (float*)d_out;

    char* ws = (char*)d_ws;
    unsigned short* Qb = (unsigned short*)(ws);                       // 2 MiB
    unsigned short* Kb = (unsigned short*)(ws + (2u << 20));          // 2 MiB
    unsigned short* Vt = (unsigned short*)(ws + (4u << 20));          // 2 MiB
    unsigned short* Wfrag = (unsigned short*)(ws + (6u << 20));       // 384 KiB
    float* bias        = (float*)(ws + (6u << 20) + 3 * DH * DIN * 2); // 64 KiB

    prep_kernel<<<832, 256, 0, stream>>>(Wq, Wk, Wv, mask, Wfrag, bias);
    qkv_kernel<<<512, 256, 0, stream>>>(X, Wfrag, bq, bk, bv, Qb, Kb, Vt);
    attn_kernel<<<512, 256, 0, stream>>>(Qb, Kb, Vt, bias, out);
}